// Round 3
// baseline (686.809 us; speedup 1.0000x reference)
//
#include <hip/hip_runtime.h>
#include <hip/hip_bf16.h>
#include <stdint.h>

// MLA decode: B=32, H=32, KV_LORA=512, ROPE=64, NOPE=128, VH=128, QL=1536,
// HID=5120, BLK=128, 32 blocks/seq, NB=1024. fp32 in/out, bf16 MFMA internals.
// R6: de-atomicize K1/K2 (plain-store partials). WIN: 693 -> 648 us.
//     => fp32 device atomicAdd ~10ns each aggregate; plain-store round-trips
//     through L2/L3 are much cheaper.
// R7: de-atomicize EVERYTHING. K3 -> num_part[16][...]/den_part plain slabs;
//     K4 rebuilt to sum 16 partials at staging and plain-store o_acc;
//     K5 -> out_part[16][...] plain slabs; new K6 sums them into out.
//     Removes remaining ~11.5M atomics and BOTH memsets.

typedef __attribute__((ext_vector_type(8))) short short8;
typedef __attribute__((ext_vector_type(4))) float f32x4;

__device__ inline uint32_t f2bf(float f) {
  uint32_t u = __float_as_uint(f);
  return (u + 0x7fffu + ((u >> 16) & 1u)) >> 16;   // RNE
}
// packed f32x2 -> bf16x2 via v_cvt_pk_bf16_f32 (gfx950)
union Bf2U { __hip_bfloat162 h; uint32_t u; };
__device__ inline uint32_t pack2bf(float lo, float hi) {
  Bf2U v; v.h = __float22bfloat162_rn(float2{lo, hi});
  return v.u;
}
union FragU { uint32_t u[4]; short8 s; };
__device__ inline short8 frag_from(const uint32_t r[4]) {
  FragU v; v.u[0] = r[0]; v.u[1] = r[1]; v.u[2] = r[2]; v.u[3] = r[3];
  return v.s;
}

// ---------------------------------------------------------------- K1: q proj
// out[b][c] = sum_k hidden[b][k] * W[k][c], W = [W_Q (4096 cols) | W_QR (2048)]
// grid (48 col-tiles of 128, 12 k-splits of 128) = 576 blocks (2.25/CU).
// Plain float4 stores of per-ksplit partials into q_part[ks][b][gcol].
__global__ __launch_bounds__(256) void k1_qproj(
    const float* __restrict__ hidden, const float* __restrict__ W_Q,
    const float* __restrict__ W_QR, float* __restrict__ q_part) {
  __shared__ float hl[32][129];
  const int t = threadIdx.x;
  const int ctile = blockIdx.x * 128;
  const int k0 = blockIdx.y * 128;
  const bool isQ = (ctile < 4096);
  const float* W = isQ ? W_Q : W_QR;
  const int wstride = isQ ? 4096 : 2048;
  const int c = (isQ ? ctile : ctile - 4096) + (t & 31) * 4;
  const int gcol = ctile + (t & 31) * 4;   // unified output column
  const int rg = t >> 5;  // 8 groups x 4 batch rows
  for (int idx = t; idx < 4096; idx += 256) {
    int b = idx >> 7, kk = idx & 127;
    hl[b][kk] = hidden[b * 1536 + k0 + kk];
  }
  __syncthreads();
  float acc[4][4];
#pragma unroll
  for (int r = 0; r < 4; ++r)
#pragma unroll
    for (int j = 0; j < 4; ++j) acc[r][j] = 0.f;
  const float* wp = W + (size_t)k0 * wstride + c;
#pragma unroll 4
  for (int kk = 0; kk < 128; ++kk) {
    float4 w = *(const float4*)wp;
    wp += wstride;
#pragma unroll
    for (int r = 0; r < 4; ++r) {
      float hv = hl[rg * 4 + r][kk];
      acc[r][0] += hv * w.x;
      acc[r][1] += hv * w.y;
      acc[r][2] += hv * w.z;
      acc[r][3] += hv * w.w;
    }
  }
  float* dst = q_part + (size_t)blockIdx.y * 32 * 6144;
#pragma unroll
  for (int r = 0; r < 4; ++r) {
    float4 v = make_float4(acc[r][0], acc[r][1], acc[r][2], acc[r][3]);
    *(float4*)&dst[(size_t)(rg * 4 + r) * 6144 + gcol] = v;
  }
}

// --------------------------------------------------------------- K2: q_lora
// q_acc2[ds][b][h][c] = sum_{d in split} q_nope[b][h*128+d] * W_UK[h][d][c]
// q_nope reconstructed by summing K1's 12 partials at staging (L2-resident).
// grid (4 c-tiles of 128, 32 heads, 4 d-splits of 32) = 512 blocks (2/CU).
__global__ __launch_bounds__(256) void k2_qlora(
    const float* __restrict__ q_part, const float* __restrict__ W_UK,
    float* __restrict__ q_acc2) {
  __shared__ float qn[32][33];
  const int t = threadIdx.x;
  const int h = blockIdx.y;
  const int c0 = blockIdx.x * 128;
  const int d0 = blockIdx.z * 32;
  for (int idx = t; idx < 1024; idx += 256) {
    int b = idx >> 5, dd = idx & 31;
    const int col = h * 128 + d0 + dd;
    float s = 0.f;
#pragma unroll
    for (int ks = 0; ks < 12; ++ks)
      s += q_part[(size_t)(ks * 32 + b) * 6144 + col];
    qn[b][dd] = s;
  }
  __syncthreads();
  const int c = c0 + (t & 31) * 4;
  const int rg = t >> 5;  // 8 groups x 4 batch rows
  float acc[4][4];
#pragma unroll
  for (int r = 0; r < 4; ++r)
#pragma unroll
    for (int j = 0; j < 4; ++j) acc[r][j] = 0.f;
  const float* wp = W_UK + (size_t)(h * 128 + d0) * 512 + c;
#pragma unroll 4
  for (int dd = 0; dd < 32; ++dd) {
    float4 w = *(const float4*)wp;
    wp += 512;
#pragma unroll
    for (int r = 0; r < 4; ++r) {
      float qv = qn[rg * 4 + r][dd];
      acc[r][0] += qv * w.x;
      acc[r][1] += qv * w.y;
      acc[r][2] += qv * w.z;
      acc[r][3] += qv * w.w;
    }
  }
  const int ds = blockIdx.z;
  float* dst = q_acc2 + (size_t)ds * 524288;  // [32][32][512] per split
#pragma unroll
  for (int r = 0; r < 4; ++r) {
    float4 v = make_float4(acc[r][0], acc[r][1], acc[r][2], acc[r][3]);
    *(float4*)&dst[(size_t)((rg * 4 + r) * 32 + h) * 512 + c] = v;
  }
}

// ------------------------- K2b: RoPE + cache scatter + q->bf16 convert
// grid (32 seqs, 8 head-slices of 4) = 256 blocks. Sums K2's 4 d-split
// partials during convert; sums K1's 12 partials for the q-rope slice.
__global__ __launch_bounds__(256) void k2b_rope_scatter(
    const float* __restrict__ q_part, const float* __restrict__ k_pe,
    const float* __restrict__ k_c_normed, const int* __restrict__ ipos,
    const int* __restrict__ bindices, const int* __restrict__ boffsets,
    const float* __restrict__ q_acc2, float* __restrict__ cache_k,
    float* __restrict__ cache_v, uint16_t* __restrict__ q_bf) {
  const int b = blockIdx.x;
  const int hs = blockIdx.y * 4;   // 4 heads per block
  const int t = threadIdx.x;
  const float pos = (float)ipos[b];
  const float scale = 0.07216878364870323f;  // 1/sqrt(192)
  const float lnk = 0.28782313662425575f;    // ln(10000)/32
  // nope part: sum 4 d-split partials + scale + convert (4 heads x 512 c)
  for (int idx = t; idx < 2048; idx += 256) {
    int h = hs + (idx >> 9), c = idx & 511;
    const size_t base = (size_t)(b * 32 + h) * 512 + c;
    float s = q_acc2[base] + q_acc2[base + 524288] +
              q_acc2[base + 2 * 524288] + q_acc2[base + 3 * 524288];
    q_bf[((size_t)b * 32 + h) * 576 + c] = (uint16_t)f2bf(s * scale);
  }
  // rope part of q (4 heads x 32 pairs); q_pe lives at cols 4096+ of q_part
  if (t < 128) {
    int h = hs + (t >> 5), i = t & 31;
    float ang = pos * __expf(-(float)i * lnk);
    float s, c;
    sincosf(ang, &s, &c);
    float x1 = 0.f, x2 = 0.f;
    const int col = 4096 + h * 64 + i;
#pragma unroll
    for (int ks = 0; ks < 12; ++ks) {
      const float* p = q_part + (size_t)(ks * 32 + b) * 6144 + col;
      x1 += p[0];
      x2 += p[32];
    }
    int base = (b * 32 + h) * 576 + 512;
    q_bf[base + i]      = (uint16_t)f2bf((x1 * c - x2 * s) * scale);
    q_bf[base + 32 + i] = (uint16_t)f2bf((x2 * c + x1 * s) * scale);
  }
  if (blockIdx.y == 0) {
    const int row = bindices[b] * 128 + boffsets[b];
    if (t < 32) {
      int i = t;
      float ang = pos * __expf(-(float)i * lnk);
      float s, c;
      sincosf(ang, &s, &c);
      float x1 = k_pe[b * 64 + i], x2 = k_pe[b * 64 + 32 + i];
      cache_k[row * 64 + i]      = x1 * c - x2 * s;
      cache_k[row * 64 + 32 + i] = x2 * c + x1 * s;
    }
    for (int j = t; j < 512; j += 256)
      cache_v[row * 512 + j] = k_c_normed[b * 512 + j];
  }
}

// ------------------------------------------------------------ K3: attention
// grid (16 parts, 32 seqs), 256 thr (4 waves), 2 blocks/WG, 32-kv sub-tiles.
// LDS tile Tl: d-pair-zip  Tl[d2*33+kv] = {T[kv][2d2], T[kv][2d2+1]} (bf16 pair)
// R7: partial num/den written as plain stores into private per-(part,g)
// slabs (num_part 33.5 MB, den_part 64 KB) -- zero atomics.
__global__ __launch_bounds__(256, 2) void k3_attn(
    const uint16_t* __restrict__ q_bf, const float* __restrict__ cache_k,
    const float* __restrict__ cache_v, const int* __restrict__ block_list,
    const int* __restrict__ block_groups, const float* __restrict__ block_bias,
    float* __restrict__ num_part, float* __restrict__ den_part) {
  __shared__ uint32_t Tl[288 * 33];
  __shared__ uint32_t Pl[16 * 33];
  __shared__ float den_sh[2][32];

  const int t = threadIdx.x;
  const int part = blockIdx.x, bseq = blockIdx.y;
  const int wave = t >> 6, lane = t & 63, quad = lane >> 4, l16 = lane & 15;
  const int hh = wave >> 1, kvh = wave & 1;
  const int n0 = bseq * 32 + part * 2;
  const int g = block_groups[n0];

  // Q fragments (this wave's 16-head half), 72 dwords in registers
  uint32_t qf[72];
  {
    const uint32_t* qrow =
        (const uint32_t*)(q_bf + (size_t)(g * 32 + hh * 16 + l16) * 576);
#pragma unroll
    for (int ks = 0; ks < 18; ++ks)
#pragma unroll
      for (int i = 0; i < 4; ++i)
        qf[ks * 4 + i] = qrow[ks * 16 + quad * 4 + i];
  }

  const f32x4 fzero = {0.f, 0.f, 0.f, 0.f};
  f32x4 acc[2][8];
#pragma unroll
  for (int mt = 0; mt < 2; ++mt)
#pragma unroll
    for (int nt = 0; nt < 8; ++nt) acc[mt][nt] = fzero;
  float den_acc_r[4] = {0.f, 0.f, 0.f, 0.f};

  for (int blk_i = 0; blk_i < 2; ++blk_i) {
    const int n = n0 + blk_i;
    const int phys = block_list[n];
    const float* vrow = cache_v + (size_t)phys * 128 * 512;
    const float* krow = cache_k + (size_t)phys * 128 * 64;
    for (int s = 0; s < 4; ++s) {
      const int s0 = s * 32;
      __syncthreads();  // previous PV readers done
      // stage V: 32 kv x 512 d = 4096 float4 (no divide, no branch)
#pragma unroll
      for (int i = 0; i < 16; ++i) {
        int idx = i * 256 + t;
        int kv = idx >> 7, f4 = idx & 127;
        float4 v = *(const float4*)(vrow + (s0 + kv) * 512 + f4 * 4);
        int d2 = f4 * 2;
        Tl[(d2    ) * 33 + kv] = pack2bf(v.x, v.y);
        Tl[(d2 + 1) * 33 + kv] = pack2bf(v.z, v.w);
      }
      // stage K: 32 kv x 64 d = 512 float4
#pragma unroll
      for (int i = 0; i < 2; ++i) {
        int idx = i * 256 + t;
        int kv = idx >> 4, f4 = idx & 15;
        float4 v = *(const float4*)(krow + (s0 + kv) * 64 + f4 * 4);
        int d2 = 256 + f4 * 2;
        Tl[(d2    ) * 33 + kv] = pack2bf(v.x, v.y);
        Tl[(d2 + 1) * 33 + kv] = pack2bf(v.z, v.w);
      }
      __syncthreads();
      // ---- logits: wave computes 16h x 16kv tile (hh, kvh), K = 576
      const int tkv = kvh * 16 + l16;
      f32x4 lg = fzero;
#pragma unroll
      for (int ks = 0; ks < 18; ++ks) {
        uint32_t br[4];
#pragma unroll
        for (int i = 0; i < 4; ++i)
          br[i] = Tl[(ks * 16 + quad * 4 + i) * 33 + tkv];
        lg = __builtin_amdgcn_mfma_f32_16x16x32_bf16(
            frag_from(&qf[ks * 4]), frag_from(br), lg, 0, 0, 0);
      }
      float bias = block_bias[n * 128 + s0 + tkv];
      uint32_t pb[4];
#pragma unroll
      for (int r = 0; r < 4; ++r) {
        float p = __expf(lg[r] + bias);   // no shift: |logit| <= ~9, safe
        pb[r] = f2bf(p);
        den_acc_r[r] += __uint_as_float(pb[r] << 16);
      }
#pragma unroll
      for (int r = 0; r < 4; ++r) {       // kv-pair-zip P into LDS
        uint32_t other = (uint32_t)__shfl_xor((int)pb[r], 1, 64);
        if ((l16 & 1) == 0) {
          int h = hh * 16 + quad * 4 + r;
          Pl[(tkv >> 1) * 33 + h] = pb[r] | (other << 16);
        }
      }
      __syncthreads();
      // ---- PV: wave handles l-slice [wave*128, wave*128+128)
      uint32_t af[2][4];
#pragma unroll
      for (int mt = 0; mt < 2; ++mt)
#pragma unroll
        for (int i = 0; i < 4; ++i)
          af[mt][i] = Pl[(quad * 4 + i) * 33 + mt * 16 + l16];
#pragma unroll
      for (int nt = 0; nt < 8; ++nt) {
        int l = wave * 128 + nt * 16 + l16;
        const uint32_t* base = &Tl[(l >> 1) * 33 + quad * 8];
        uint32_t dw[8];
#pragma unroll
        for (int j = 0; j < 8; ++j) dw[j] = base[j];
        uint32_t br[4];
        const bool odd = (l & 1);
#pragma unroll
        for (int i = 0; i < 4; ++i) {
          uint32_t a = dw[2 * i], bq = dw[2 * i + 1];
          uint32_t lo = odd ? (a >> 16) : (a & 0xffffu);
          uint32_t hi = odd ? (bq & 0xffff0000u) : (bq << 16);
          br[i] = lo | hi;
        }
        short8 bf = frag_from(br);
        acc[0][nt] = __builtin_amdgcn_mfma_f32_16x16x32_bf16(
            frag_from(af[0]), bf, acc[0][nt], 0, 0, 0);
        acc[1][nt] = __builtin_amdgcn_mfma_f32_16x16x32_bf16(
            frag_from(af[1]), bf, acc[1][nt], 0, 0, 0);
      }
    }
  }
  // num partial: plain stores into this WG's private slab (64 KB contiguous)
  float* npart = num_part + (size_t)(part * 32 + g) * 32 * 512;
#pragma unroll
  for (int mt = 0; mt < 2; ++mt)
#pragma unroll
    for (int nt = 0; nt < 8; ++nt)
#pragma unroll
      for (int r = 0; r < 4; ++r) {
        int h = mt * 16 + quad * 4 + r;
        int l = wave * 128 + nt * 16 + l16;
        npart[(size_t)h * 512 + l] = acc[mt][nt][r];
      }
  // den partial: reduce over 16 kv lanes, combine kv-halves via LDS
  float dv[4];
#pragma unroll
  for (int r = 0; r < 4; ++r) {
    float v = den_acc_r[r];
    v += __shfl_xor(v, 1, 64);
    v += __shfl_xor(v, 2, 64);
    v += __shfl_xor(v, 4, 64);
    v += __shfl_xor(v, 8, 64);
    dv[r] = v;
  }
  if (l16 == 0) {
#pragma unroll
    for (int r = 0; r < 4; ++r)
      den_sh[kvh][hh * 16 + quad * 4 + r] = dv[r];
  }
  __syncthreads();
  if (t < 32)
    den_part[(size_t)(part * 32 + g) * 32 + t] = den_sh[0][t] + den_sh[1][t];
}

// --------------------------------------------- K4: sum parts + divide + W_UV
// grid (4 b-groups of 8, 32 heads) = 128 blocks. Sums 16 num/den partials at
// staging (each element read once), plain-stores o_acc (each written once).
__global__ __launch_bounds__(256) void k4_reduce_wuv(
    const float* __restrict__ num_part, const float* __restrict__ den_part,
    const float* __restrict__ W_UV, float* __restrict__ o_acc) {
  __shared__ float attn[8][516];
  __shared__ float inv[8];
  const int t = threadIdx.x;
  const int bg = blockIdx.x;
  const int h = blockIdx.y;
  if (t < 128) {
    int b = t >> 4, p = t & 15;
    float v = den_part[(size_t)(p * 32 + bg * 8 + b) * 32 + h];
    v += __shfl_xor(v, 1, 64);
    v += __shfl_xor(v, 2, 64);
    v += __shfl_xor(v, 4, 64);
    v += __shfl_xor(v, 8, 64);
    if (p == 0) inv[b] = 1.f / v;
  }
  __syncthreads();
  for (int idx = t; idx < 4096; idx += 256) {
    int b = idx >> 9, l = idx & 511;
    const float* np =
        num_part + ((size_t)(bg * 8 + b) * 32 + h) * 512 + l;
    float s = 0.f;
#pragma unroll
    for (int p = 0; p < 16; ++p) s += np[(size_t)p * 524288];
    attn[b][l] = s * inv[b];
  }
  __syncthreads();
  const int v = t & 127, rg = t >> 7;
  float acc[4] = {0.f, 0.f, 0.f, 0.f};
  const float* wp = W_UV + (size_t)h * 512 * 128 + v;
#pragma unroll 4
  for (int l = 0; l < 512; ++l) {
    float w = *wp;
    wp += 128;
#pragma unroll
    for (int r = 0; r < 4; ++r) acc[r] += attn[rg * 4 + r][l] * w;
  }
#pragma unroll
  for (int r = 0; r < 4; ++r)
    o_acc[(size_t)(bg * 8 + rg * 4 + r) * 4096 + h * 128 + v] = acc[r];
}

// -------------------------------------------------------- K5: o @ W_O
// grid (16 k-splits of 256, 40 n-tiles of 128), bf16 MFMA, float4 staging,
// plain stores into per-ksplit slab out_part[ks][b][c].
__global__ __launch_bounds__(256) void k5_wo(
    const float* __restrict__ o_acc, const float* __restrict__ W_O,
    float* __restrict__ out_part) {
  __shared__ uint32_t Bt[32 * 130];  // k-pair-zip of a 64k x 128n W_O chunk
  const int t = threadIdx.x;
  const int ksplit = blockIdx.x, ntile = blockIdx.y;
  const int n0 = ntile * 128, kbase = ksplit * 256;
  const int wave = t >> 6, lane = t & 63, quad = lane >> 4, l16 = lane & 15;
  const f32x4 fzero = {0.f, 0.f, 0.f, 0.f};
  f32x4 acc[2][2];
#pragma unroll
  for (int mt = 0; mt < 2; ++mt)
#pragma unroll
    for (int nt = 0; nt < 2; ++nt) acc[mt][nt] = fzero;
  for (int kc = 0; kc < 4; ++kc) {
    const int k0 = kbase + kc * 64;
    __syncthreads();
    for (int idx = t; idx < 1024; idx += 256) {  // k2 in [0,32) x c4 in [0,32)
      int k2 = idx >> 5, c4 = idx & 31;
      const float* p0 = &W_O[(size_t)(k0 + 2 * k2) * 5120 + n0 + c4 * 4];
      float4 a = *(const float4*)p0;
      float4 b = *(const float4*)(p0 + 5120);
      uint32_t* bp = &Bt[k2 * 130 + c4 * 4];
      bp[0] = pack2bf(a.x, b.x);
      bp[1] = pack2bf(a.y, b.y);
      bp[2] = pack2bf(a.z, b.z);
      bp[3] = pack2bf(a.w, b.w);
    }
    __syncthreads();
#pragma unroll
    for (int ks2 = 0; ks2 < 2; ++ks2) {
      uint32_t af[2][4];
#pragma unroll
      for (int mt = 0; mt < 2; ++mt) {
        const float* orow =
            o_acc + (size_t)(mt * 16 + l16) * 4096 + k0 + ks2 * 32 + quad * 8;
        float4 x = *(const float4*)orow;
        float4 y = *(const float4*)(orow + 4);
        af[mt][0] = pack2bf(x.x, x.y);
        af[mt][1] = pack2bf(x.z, x.w);
        af[mt][2] = pack2bf(y.x, y.y);
        af[mt][3] = pack2bf(y.z, y.w);
      }
#pragma unroll
      for (int nt = 0; nt < 2; ++nt) {
        uint32_t br[4];
#pragma unroll
        for (int i = 0; i < 4; ++i)
          br[i] = Bt[(ks2 * 16 + quad * 4 + i) * 130 + wave * 32 + nt * 16 + l16];
        short8 bf = frag_from(br);
        acc[0][nt] = __builtin_amdgcn_mfma_f32_16x16x32_bf16(
            frag_from(af[0]), bf, acc[0][nt], 0, 0, 0);
        acc[1][nt] = __builtin_amdgcn_mfma_f32_16x16x32_bf16(
            frag_from(af[1]), bf, acc[1][nt], 0, 0, 0);
      }
    }
  }
  float* dst = out_part + (size_t)ksplit * 32 * 5120;
#pragma unroll
  for (int mt = 0; mt < 2; ++mt)
#pragma unroll
    for (int nt = 0; nt < 2; ++nt)
#pragma unroll
      for (int r = 0; r < 4; ++r) {
        int b = mt * 16 + quad * 4 + r;
        int c = n0 + wave * 32 + nt * 16 + l16;
        dst[(size_t)b * 5120 + c] = acc[mt][nt][r];
      }
}

// -------------------------------------------------------- K6: out = sum parts
// grid (32 b, 5 c-chunks of 1024), 256 thr, float4.
__global__ __launch_bounds__(256) void k6_outsum(
    const float* __restrict__ out_part, float* __restrict__ out) {
  const int b = blockIdx.x;
  const int c4 = blockIdx.y * 1024 + threadIdx.x * 4;
  const float* p = out_part + (size_t)b * 5120 + c4;
  float4 s = *(const float4*)p;
#pragma unroll
  for (int ks = 1; ks < 16; ++ks) {
    float4 v = *(const float4*)(p + (size_t)ks * 163840);
    s.x += v.x; s.y += v.y; s.z += v.z; s.w += v.w;
  }
  *(float4*)&out[(size_t)b * 5120 + c4] = s;
}

extern "C" void kernel_launch(void* const* d_in, const int* in_sizes, int n_in,
                              void* d_out, int out_size, void* d_ws,
                              size_t ws_size, hipStream_t stream) {
  (void)in_sizes; (void)n_in; (void)ws_size; (void)out_size;
  const float* hidden = (const float*)d_in[0];
  const float* k_c    = (const float*)d_in[1];
  const float* k_pe   = (const float*)d_in[2];
  float* cache_k      = (float*)d_in[3];
  float* cache_v      = (float*)d_in[4];
  const float* W_Q    = (const float*)d_in[5];
  const float* W_UK   = (const float*)d_in[6];
  const float* W_QR   = (const float*)d_in[7];
  const float* W_UV   = (const float*)d_in[8];
  const float* W_O    = (const float*)d_in[9];
  const int* ipos     = (const int*)d_in[10];
  const int* blist    = (const int*)d_in[11];
  const int* bgroups  = (const int*)d_in[12];
  const float* bbias  = (const float*)d_in[13];
  const int* bindices = (const int*)d_in[14];
  const int* boffsets = (const int*)d_in[15];

  char* ws = (char*)d_ws;
  // all buffers fully written before read -- NO memsets, NO atomics.
  float*    q_part   = (float*)(ws);                 //  9437184 B [12][32][6144]
  float*    q_acc2   = (float*)(ws + 9437184);       //  8388608 B [4][32][32][512]
  uint16_t* q_bf     = (uint16_t*)(ws + 17825792);   //  1179648 B
  float*    num_part = (float*)(ws + 19005440);      // 33554432 B [16][32][32][512]
  float*    den_part = (float*)(ws + 52559872);      //    65536 B [16][32][32]
  float*    o_acc    = (float*)(ws + 52625408);      //   524288 B [32][4096]
  float*    out_part = (float*)(ws + 53149696);      // 10485760 B [16][32][5120]
  float*    out      = (float*)d_out;

  k1_qproj<<<dim3(48, 12), 256, 0, stream>>>(hidden, W_Q, W_QR, q_part);
  k2_qlora<<<dim3(4, 32, 4), 256, 0, stream>>>(q_part, W_UK, q_acc2);
  k2b_rope_scatter<<<dim3(32, 8), 256, 0, stream>>>(q_part, k_pe, k_c, ipos,
                                                    bindices, boffsets, q_acc2,
                                                    cache_k, cache_v, q_bf);
  k3_attn<<<dim3(16, 32), 256, 0, stream>>>(q_bf, cache_k, cache_v, blist,
                                            bgroups, bbias, num_part, den_part);
  k4_reduce_wuv<<<dim3(4, 32), 256, 0, stream>>>(num_part, den_part, W_UV,
                                                 o_acc);
  k5_wo<<<dim3(16, 40), 256, 0, stream>>>(o_acc, W_O, out_part);
  k6_outsum<<<dim3(32, 5), 256, 0, stream>>>(out_part, out);
}

// Round 4
// 646.798 us; speedup vs baseline: 1.0619x; 1.0619x over previous
//
#include <hip/hip_runtime.h>
#include <hip/hip_bf16.h>
#include <stdint.h>

// MLA decode: B=32, H=32, KV_LORA=512, ROPE=64, NOPE=128, VH=128, QL=1536,
// HID=5120, BLK=128, 32 blocks/seq, NB=1024. fp32 in/out, bf16 MFMA internals.
// R6: de-atomicize K1/K2 (plain-store partials). WIN: 693 -> 648 us.
// R7: de-atomicize everything. REGRESSED 648 -> 687. Lesson: atomic cost is
//     about BURST RATE, not count. K3's 8.4M atomics spread over a long
//     memory-bound kernel are ~free; replacing them with a 33.5 MB round-trip
//     + an underutilized K4 rebuild cost ~40 us.
// R8: revert K3/K4 to R6's atomic forms. Keep ONLY the R7 sub-change that
//     matches the burst model: K5 (short kernel, 2.6M bursty 16-way atomics
//     into 655 KB out) now plain-stores per-ksplit slabs; K6 sums them.
//     d_out memset dropped (K6 fully writes it).

typedef __attribute__((ext_vector_type(8))) short short8;
typedef __attribute__((ext_vector_type(4))) float f32x4;

__device__ inline uint32_t f2bf(float f) {
  uint32_t u = __float_as_uint(f);
  return (u + 0x7fffu + ((u >> 16) & 1u)) >> 16;   // RNE
}
// packed f32x2 -> bf16x2 via v_cvt_pk_bf16_f32 (gfx950)
union Bf2U { __hip_bfloat162 h; uint32_t u; };
__device__ inline uint32_t pack2bf(float lo, float hi) {
  Bf2U v; v.h = __float22bfloat162_rn(float2{lo, hi});
  return v.u;
}
union FragU { uint32_t u[4]; short8 s; };
__device__ inline short8 frag_from(const uint32_t r[4]) {
  FragU v; v.u[0] = r[0]; v.u[1] = r[1]; v.u[2] = r[2]; v.u[3] = r[3];
  return v.s;
}

// ---------------------------------------------------------------- K1: q proj
// out[b][c] = sum_k hidden[b][k] * W[k][c], W = [W_Q (4096 cols) | W_QR (2048)]
// grid (48 col-tiles of 128, 12 k-splits of 128) = 576 blocks (2.25/CU).
// Plain float4 stores of per-ksplit partials into q_part[ks][b][gcol].
__global__ __launch_bounds__(256) void k1_qproj(
    const float* __restrict__ hidden, const float* __restrict__ W_Q,
    const float* __restrict__ W_QR, float* __restrict__ q_part) {
  __shared__ float hl[32][129];
  const int t = threadIdx.x;
  const int ctile = blockIdx.x * 128;
  const int k0 = blockIdx.y * 128;
  const bool isQ = (ctile < 4096);
  const float* W = isQ ? W_Q : W_QR;
  const int wstride = isQ ? 4096 : 2048;
  const int c = (isQ ? ctile : ctile - 4096) + (t & 31) * 4;
  const int gcol = ctile + (t & 31) * 4;   // unified output column
  const int rg = t >> 5;  // 8 groups x 4 batch rows
  for (int idx = t; idx < 4096; idx += 256) {
    int b = idx >> 7, kk = idx & 127;
    hl[b][kk] = hidden[b * 1536 + k0 + kk];
  }
  __syncthreads();
  float acc[4][4];
#pragma unroll
  for (int r = 0; r < 4; ++r)
#pragma unroll
    for (int j = 0; j < 4; ++j) acc[r][j] = 0.f;
  const float* wp = W + (size_t)k0 * wstride + c;
#pragma unroll 4
  for (int kk = 0; kk < 128; ++kk) {
    float4 w = *(const float4*)wp;
    wp += wstride;
#pragma unroll
    for (int r = 0; r < 4; ++r) {
      float hv = hl[rg * 4 + r][kk];
      acc[r][0] += hv * w.x;
      acc[r][1] += hv * w.y;
      acc[r][2] += hv * w.z;
      acc[r][3] += hv * w.w;
    }
  }
  float* dst = q_part + (size_t)blockIdx.y * 32 * 6144;
#pragma unroll
  for (int r = 0; r < 4; ++r) {
    float4 v = make_float4(acc[r][0], acc[r][1], acc[r][2], acc[r][3]);
    *(float4*)&dst[(size_t)(rg * 4 + r) * 6144 + gcol] = v;
  }
}

// --------------------------------------------------------------- K2: q_lora
// q_acc2[ds][b][h][c] = sum_{d in split} q_nope[b][h*128+d] * W_UK[h][d][c]
// q_nope reconstructed by summing K1's 12 partials at staging (L2-resident).
// grid (4 c-tiles of 128, 32 heads, 4 d-splits of 32) = 512 blocks (2/CU).
__global__ __launch_bounds__(256) void k2_qlora(
    const float* __restrict__ q_part, const float* __restrict__ W_UK,
    float* __restrict__ q_acc2) {
  __shared__ float qn[32][33];
  const int t = threadIdx.x;
  const int h = blockIdx.y;
  const int c0 = blockIdx.x * 128;
  const int d0 = blockIdx.z * 32;
  for (int idx = t; idx < 1024; idx += 256) {
    int b = idx >> 5, dd = idx & 31;
    const int col = h * 128 + d0 + dd;
    float s = 0.f;
#pragma unroll
    for (int ks = 0; ks < 12; ++ks)
      s += q_part[(size_t)(ks * 32 + b) * 6144 + col];
    qn[b][dd] = s;
  }
  __syncthreads();
  const int c = c0 + (t & 31) * 4;
  const int rg = t >> 5;  // 8 groups x 4 batch rows
  float acc[4][4];
#pragma unroll
  for (int r = 0; r < 4; ++r)
#pragma unroll
    for (int j = 0; j < 4; ++j) acc[r][j] = 0.f;
  const float* wp = W_UK + (size_t)(h * 128 + d0) * 512 + c;
#pragma unroll 4
  for (int dd = 0; dd < 32; ++dd) {
    float4 w = *(const float4*)wp;
    wp += 512;
#pragma unroll
    for (int r = 0; r < 4; ++r) {
      float qv = qn[rg * 4 + r][dd];
      acc[r][0] += qv * w.x;
      acc[r][1] += qv * w.y;
      acc[r][2] += qv * w.z;
      acc[r][3] += qv * w.w;
    }
  }
  const int ds = blockIdx.z;
  float* dst = q_acc2 + (size_t)ds * 524288;  // [32][32][512] per split
#pragma unroll
  for (int r = 0; r < 4; ++r) {
    float4 v = make_float4(acc[r][0], acc[r][1], acc[r][2], acc[r][3]);
    *(float4*)&dst[(size_t)((rg * 4 + r) * 32 + h) * 512 + c] = v;
  }
}

// ------------------------- K2b: RoPE + cache scatter + q->bf16 convert
// grid (32 seqs, 8 head-slices of 4) = 256 blocks. Sums K2's 4 d-split
// partials during convert; sums K1's 12 partials for the q-rope slice.
__global__ __launch_bounds__(256) void k2b_rope_scatter(
    const float* __restrict__ q_part, const float* __restrict__ k_pe,
    const float* __restrict__ k_c_normed, const int* __restrict__ ipos,
    const int* __restrict__ bindices, const int* __restrict__ boffsets,
    const float* __restrict__ q_acc2, float* __restrict__ cache_k,
    float* __restrict__ cache_v, uint16_t* __restrict__ q_bf) {
  const int b = blockIdx.x;
  const int hs = blockIdx.y * 4;   // 4 heads per block
  const int t = threadIdx.x;
  const float pos = (float)ipos[b];
  const float scale = 0.07216878364870323f;  // 1/sqrt(192)
  const float lnk = 0.28782313662425575f;    // ln(10000)/32
  // nope part: sum 4 d-split partials + scale + convert (4 heads x 512 c)
  for (int idx = t; idx < 2048; idx += 256) {
    int h = hs + (idx >> 9), c = idx & 511;
    const size_t base = (size_t)(b * 32 + h) * 512 + c;
    float s = q_acc2[base] + q_acc2[base + 524288] +
              q_acc2[base + 2 * 524288] + q_acc2[base + 3 * 524288];
    q_bf[((size_t)b * 32 + h) * 576 + c] = (uint16_t)f2bf(s * scale);
  }
  // rope part of q (4 heads x 32 pairs); q_pe lives at cols 4096+ of q_part
  if (t < 128) {
    int h = hs + (t >> 5), i = t & 31;
    float ang = pos * __expf(-(float)i * lnk);
    float s, c;
    sincosf(ang, &s, &c);
    float x1 = 0.f, x2 = 0.f;
    const int col = 4096 + h * 64 + i;
#pragma unroll
    for (int ks = 0; ks < 12; ++ks) {
      const float* p = q_part + (size_t)(ks * 32 + b) * 6144 + col;
      x1 += p[0];
      x2 += p[32];
    }
    int base = (b * 32 + h) * 576 + 512;
    q_bf[base + i]      = (uint16_t)f2bf((x1 * c - x2 * s) * scale);
    q_bf[base + 32 + i] = (uint16_t)f2bf((x2 * c + x1 * s) * scale);
  }
  if (blockIdx.y == 0) {
    const int row = bindices[b] * 128 + boffsets[b];
    if (t < 32) {
      int i = t;
      float ang = pos * __expf(-(float)i * lnk);
      float s, c;
      sincosf(ang, &s, &c);
      float x1 = k_pe[b * 64 + i], x2 = k_pe[b * 64 + 32 + i];
      cache_k[row * 64 + i]      = x1 * c - x2 * s;
      cache_k[row * 64 + 32 + i] = x2 * c + x1 * s;
    }
    for (int j = t; j < 512; j += 256)
      cache_v[row * 512 + j] = k_c_normed[b * 512 + j];
  }
}

// ------------------------------------------------------------ K3: attention
// grid (16 parts, 32 seqs), 256 thr (4 waves), 2 blocks/WG, 32-kv sub-tiles.
// LDS tile Tl: d-pair-zip  Tl[d2*33+kv] = {T[kv][2d2], T[kv][2d2+1]} (bf16 pair)
// Partial num/den accumulated straight into global num_acc/den_acc (atomics,
// spread across the long memory-bound runtime -- measured ~free, R6 vs R7).
__global__ __launch_bounds__(256, 2) void k3_attn(
    const uint16_t* __restrict__ q_bf, const float* __restrict__ cache_k,
    const float* __restrict__ cache_v, const int* __restrict__ block_list,
    const int* __restrict__ block_groups, const float* __restrict__ block_bias,
    float* __restrict__ num_acc, float* __restrict__ den_acc) {
  __shared__ uint32_t Tl[288 * 33];
  __shared__ uint32_t Pl[16 * 33];
  __shared__ float den_sh[2][32];

  const int t = threadIdx.x;
  const int part = blockIdx.x, bseq = blockIdx.y;
  const int wave = t >> 6, lane = t & 63, quad = lane >> 4, l16 = lane & 15;
  const int hh = wave >> 1, kvh = wave & 1;
  const int n0 = bseq * 32 + part * 2;
  const int g = block_groups[n0];

  // Q fragments (this wave's 16-head half), 72 dwords in registers
  uint32_t qf[72];
  {
    const uint32_t* qrow =
        (const uint32_t*)(q_bf + (size_t)(g * 32 + hh * 16 + l16) * 576);
#pragma unroll
    for (int ks = 0; ks < 18; ++ks)
#pragma unroll
      for (int i = 0; i < 4; ++i)
        qf[ks * 4 + i] = qrow[ks * 16 + quad * 4 + i];
  }

  const f32x4 fzero = {0.f, 0.f, 0.f, 0.f};
  f32x4 acc[2][8];
#pragma unroll
  for (int mt = 0; mt < 2; ++mt)
#pragma unroll
    for (int nt = 0; nt < 8; ++nt) acc[mt][nt] = fzero;
  float den_acc_r[4] = {0.f, 0.f, 0.f, 0.f};

  for (int blk_i = 0; blk_i < 2; ++blk_i) {
    const int n = n0 + blk_i;
    const int phys = block_list[n];
    const float* vrow = cache_v + (size_t)phys * 128 * 512;
    const float* krow = cache_k + (size_t)phys * 128 * 64;
    for (int s = 0; s < 4; ++s) {
      const int s0 = s * 32;
      __syncthreads();  // previous PV readers done
      // stage V: 32 kv x 512 d = 4096 float4 (no divide, no branch)
#pragma unroll
      for (int i = 0; i < 16; ++i) {
        int idx = i * 256 + t;
        int kv = idx >> 7, f4 = idx & 127;
        float4 v = *(const float4*)(vrow + (s0 + kv) * 512 + f4 * 4);
        int d2 = f4 * 2;
        Tl[(d2    ) * 33 + kv] = pack2bf(v.x, v.y);
        Tl[(d2 + 1) * 33 + kv] = pack2bf(v.z, v.w);
      }
      // stage K: 32 kv x 64 d = 512 float4
#pragma unroll
      for (int i = 0; i < 2; ++i) {
        int idx = i * 256 + t;
        int kv = idx >> 4, f4 = idx & 15;
        float4 v = *(const float4*)(krow + (s0 + kv) * 64 + f4 * 4);
        int d2 = 256 + f4 * 2;
        Tl[(d2    ) * 33 + kv] = pack2bf(v.x, v.y);
        Tl[(d2 + 1) * 33 + kv] = pack2bf(v.z, v.w);
      }
      __syncthreads();
      // ---- logits: wave computes 16h x 16kv tile (hh, kvh), K = 576
      const int tkv = kvh * 16 + l16;
      f32x4 lg = fzero;
#pragma unroll
      for (int ks = 0; ks < 18; ++ks) {
        uint32_t br[4];
#pragma unroll
        for (int i = 0; i < 4; ++i)
          br[i] = Tl[(ks * 16 + quad * 4 + i) * 33 + tkv];
        lg = __builtin_amdgcn_mfma_f32_16x16x32_bf16(
            frag_from(&qf[ks * 4]), frag_from(br), lg, 0, 0, 0);
      }
      float bias = block_bias[n * 128 + s0 + tkv];
      uint32_t pb[4];
#pragma unroll
      for (int r = 0; r < 4; ++r) {
        float p = __expf(lg[r] + bias);   // no shift: |logit| <= ~9, safe
        pb[r] = f2bf(p);
        den_acc_r[r] += __uint_as_float(pb[r] << 16);
      }
#pragma unroll
      for (int r = 0; r < 4; ++r) {       // kv-pair-zip P into LDS
        uint32_t other = (uint32_t)__shfl_xor((int)pb[r], 1, 64);
        if ((l16 & 1) == 0) {
          int h = hh * 16 + quad * 4 + r;
          Pl[(tkv >> 1) * 33 + h] = pb[r] | (other << 16);
        }
      }
      __syncthreads();
      // ---- PV: wave handles l-slice [wave*128, wave*128+128)
      uint32_t af[2][4];
#pragma unroll
      for (int mt = 0; mt < 2; ++mt)
#pragma unroll
        for (int i = 0; i < 4; ++i)
          af[mt][i] = Pl[(quad * 4 + i) * 33 + mt * 16 + l16];
#pragma unroll
      for (int nt = 0; nt < 8; ++nt) {
        int l = wave * 128 + nt * 16 + l16;
        const uint32_t* base = &Tl[(l >> 1) * 33 + quad * 8];
        uint32_t dw[8];
#pragma unroll
        for (int j = 0; j < 8; ++j) dw[j] = base[j];
        uint32_t br[4];
        const bool odd = (l & 1);
#pragma unroll
        for (int i = 0; i < 4; ++i) {
          uint32_t a = dw[2 * i], bq = dw[2 * i + 1];
          uint32_t lo = odd ? (a >> 16) : (a & 0xffffu);
          uint32_t hi = odd ? (bq & 0xffff0000u) : (bq << 16);
          br[i] = lo | hi;
        }
        short8 bf = frag_from(br);
        acc[0][nt] = __builtin_amdgcn_mfma_f32_16x16x32_bf16(
            frag_from(af[0]), bf, acc[0][nt], 0, 0, 0);
        acc[1][nt] = __builtin_amdgcn_mfma_f32_16x16x32_bf16(
            frag_from(af[1]), bf, acc[1][nt], 0, 0, 0);
      }
    }
  }
  // accumulate num partial straight into global (coalesced over l16)
#pragma unroll
  for (int mt = 0; mt < 2; ++mt)
#pragma unroll
    for (int nt = 0; nt < 8; ++nt)
#pragma unroll
      for (int r = 0; r < 4; ++r) {
        int h = mt * 16 + quad * 4 + r;
        int l = wave * 128 + nt * 16 + l16;
        atomicAdd(&num_acc[((size_t)(g * 32 + h)) * 512 + l], acc[mt][nt][r]);
      }
  // den partial: reduce over 16 kv lanes, combine kv-halves via LDS
  float dv[4];
#pragma unroll
  for (int r = 0; r < 4; ++r) {
    float v = den_acc_r[r];
    v += __shfl_xor(v, 1, 64);
    v += __shfl_xor(v, 2, 64);
    v += __shfl_xor(v, 4, 64);
    v += __shfl_xor(v, 8, 64);
    dv[r] = v;
  }
  if (l16 == 0) {
#pragma unroll
    for (int r = 0; r < 4; ++r)
      den_sh[kvh][hh * 16 + quad * 4 + r] = dv[r];
  }
  __syncthreads();
  if (t < 32) atomicAdd(&den_acc[g * 32 + t], den_sh[0][t] + den_sh[1][t]);
}

// --------------------------------------------- K4: divide + W_UV
// grid (8 l-chunks of 64, 32 heads) = 256 blocks.
__global__ __launch_bounds__(256) void k4_reduce_wuv(
    const float* __restrict__ num_acc, const float* __restrict__ den_acc,
    const float* __restrict__ W_UV, float* __restrict__ o_acc) {
  __shared__ float attn[32][65];
  __shared__ float inv[32];
  const int t = threadIdx.x;
  const int l0 = blockIdx.x * 64;
  const int h = blockIdx.y;
  if (t < 32) inv[t] = 1.f / den_acc[t * 32 + h];
  __syncthreads();
  for (int idx = t; idx < 2048; idx += 256) {
    int b = idx >> 6, l = idx & 63;
    attn[b][l] = num_acc[((size_t)(b * 32 + h)) * 512 + l0 + l] * inv[b];
  }
  __syncthreads();
  const int v = t & 127, rg = t >> 7;
  float acc[16];
#pragma unroll
  for (int r = 0; r < 16; ++r) acc[r] = 0.f;
  const float* wp = W_UV + ((size_t)h * 512 + l0) * 128 + v;
#pragma unroll 4
  for (int l = 0; l < 64; ++l) {
    float w = *wp;
    wp += 128;
#pragma unroll
    for (int r = 0; r < 16; ++r) acc[r] += attn[rg * 16 + r][l] * w;
  }
#pragma unroll
  for (int r = 0; r < 16; ++r)
    atomicAdd(&o_acc[(size_t)(rg * 16 + r) * 4096 + h * 128 + v], acc[r]);
}

// -------------------------------------------------------- K5: o @ W_O
// grid (16 k-splits of 256, 40 n-tiles of 128), bf16 MFMA, float4 staging,
// plain stores into per-ksplit slab out_part[ks][b][c] (short kernel, bursty
// atomics would rate-limit -- R6/R8 burst model).
__global__ __launch_bounds__(256) void k5_wo(
    const float* __restrict__ o_acc, const float* __restrict__ W_O,
    float* __restrict__ out_part) {
  __shared__ uint32_t Bt[32 * 130];  // k-pair-zip of a 64k x 128n W_O chunk
  const int t = threadIdx.x;
  const int ksplit = blockIdx.x, ntile = blockIdx.y;
  const int n0 = ntile * 128, kbase = ksplit * 256;
  const int wave = t >> 6, lane = t & 63, quad = lane >> 4, l16 = lane & 15;
  const f32x4 fzero = {0.f, 0.f, 0.f, 0.f};
  f32x4 acc[2][2];
#pragma unroll
  for (int mt = 0; mt < 2; ++mt)
#pragma unroll
    for (int nt = 0; nt < 2; ++nt) acc[mt][nt] = fzero;
  for (int kc = 0; kc < 4; ++kc) {
    const int k0 = kbase + kc * 64;
    __syncthreads();
    for (int idx = t; idx < 1024; idx += 256) {  // k2 in [0,32) x c4 in [0,32)
      int k2 = idx >> 5, c4 = idx & 31;
      const float* p0 = &W_O[(size_t)(k0 + 2 * k2) * 5120 + n0 + c4 * 4];
      float4 a = *(const float4*)p0;
      float4 b = *(const float4*)(p0 + 5120);
      uint32_t* bp = &Bt[k2 * 130 + c4 * 4];
      bp[0] = pack2bf(a.x, b.x);
      bp[1] = pack2bf(a.y, b.y);
      bp[2] = pack2bf(a.z, b.z);
      bp[3] = pack2bf(a.w, b.w);
    }
    __syncthreads();
#pragma unroll
    for (int ks2 = 0; ks2 < 2; ++ks2) {
      uint32_t af[2][4];
#pragma unroll
      for (int mt = 0; mt < 2; ++mt) {
        const float* orow =
            o_acc + (size_t)(mt * 16 + l16) * 4096 + k0 + ks2 * 32 + quad * 8;
        float4 x = *(const float4*)orow;
        float4 y = *(const float4*)(orow + 4);
        af[mt][0] = pack2bf(x.x, x.y);
        af[mt][1] = pack2bf(x.z, x.w);
        af[mt][2] = pack2bf(y.x, y.y);
        af[mt][3] = pack2bf(y.z, y.w);
      }
#pragma unroll
      for (int nt = 0; nt < 2; ++nt) {
        uint32_t br[4];
#pragma unroll
        for (int i = 0; i < 4; ++i)
          br[i] = Bt[(ks2 * 16 + quad * 4 + i) * 130 + wave * 32 + nt * 16 + l16];
        short8 bf = frag_from(br);
        acc[0][nt] = __builtin_amdgcn_mfma_f32_16x16x32_bf16(
            frag_from(af[0]), bf, acc[0][nt], 0, 0, 0);
        acc[1][nt] = __builtin_amdgcn_mfma_f32_16x16x32_bf16(
            frag_from(af[1]), bf, acc[1][nt], 0, 0, 0);
      }
    }
  }
  float* dst = out_part + (size_t)ksplit * 32 * 5120;
#pragma unroll
  for (int mt = 0; mt < 2; ++mt)
#pragma unroll
    for (int nt = 0; nt < 2; ++nt)
#pragma unroll
      for (int r = 0; r < 4; ++r) {
        int b = mt * 16 + quad * 4 + r;
        int c = n0 + wave * 32 + nt * 16 + l16;
        dst[(size_t)b * 5120 + c] = acc[mt][nt][r];
      }
}

// -------------------------------------------------------- K6: out = sum parts
// grid (32 b, 5 c-chunks of 1024), 256 thr, float4. Fully writes d_out.
__global__ __launch_bounds__(256) void k6_outsum(
    const float* __restrict__ out_part, float* __restrict__ out) {
  const int b = blockIdx.x;
  const int c4 = blockIdx.y * 1024 + threadIdx.x * 4;
  const float* p = out_part + (size_t)b * 5120 + c4;
  float4 s = *(const float4*)p;
#pragma unroll
  for (int ks = 1; ks < 16; ++ks) {
    float4 v = *(const float4*)(p + (size_t)ks * 163840);
    s.x += v.x; s.y += v.y; s.z += v.z; s.w += v.w;
  }
  *(float4*)&out[(size_t)b * 5120 + c4] = s;
}

extern "C" void kernel_launch(void* const* d_in, const int* in_sizes, int n_in,
                              void* d_out, int out_size, void* d_ws,
                              size_t ws_size, hipStream_t stream) {
  (void)in_sizes; (void)n_in; (void)ws_size; (void)out_size;
  const float* hidden = (const float*)d_in[0];
  const float* k_c    = (const float*)d_in[1];
  const float* k_pe   = (const float*)d_in[2];
  float* cache_k      = (float*)d_in[3];
  float* cache_v      = (float*)d_in[4];
  const float* W_Q    = (const float*)d_in[5];
  const float* W_UK   = (const float*)d_in[6];
  const float* W_QR   = (const float*)d_in[7];
  const float* W_UV   = (const float*)d_in[8];
  const float* W_O    = (const float*)d_in[9];
  const int* ipos     = (const int*)d_in[10];
  const int* blist    = (const int*)d_in[11];
  const int* bgroups  = (const int*)d_in[12];
  const float* bbias  = (const float*)d_in[13];
  const int* bindices = (const int*)d_in[14];
  const int* boffsets = (const int*)d_in[15];

  char* ws = (char*)d_ws;
  // zeroed region (atomic targets) first, 4,722,688 B total:
  float*    o_acc    = (float*)(ws);                 //   524288 B (zeroed)
  float*    num_acc  = (float*)(ws + 524288);        //  4194304 B (zeroed)
  float*    den_acc  = (float*)(ws + 4718592);       //     4096 B (zeroed)
  // plain-store buffers (no zeroing needed):
  float*    q_part   = (float*)(ws + 4722688);       //  9437184 B [12][32][6144]
  float*    q_acc2   = (float*)(ws + 14159872);      //  8388608 B [4][32][32][512]
  uint16_t* q_bf     = (uint16_t*)(ws + 22548480);   //  1179648 B
  float*    out_part = (float*)(ws + 23728128);      // 10485760 B [16][32][5120]
  float*    out      = (float*)d_out;

  hipMemsetAsync(ws, 0, 4722688, stream);  // atomic targets only

  k1_qproj<<<dim3(48, 12), 256, 0, stream>>>(hidden, W_Q, W_QR, q_part);
  k2_qlora<<<dim3(4, 32, 4), 256, 0, stream>>>(q_part, W_UK, q_acc2);
  k2b_rope_scatter<<<dim3(32, 8), 256, 0, stream>>>(q_part, k_pe, k_c, ipos,
                                                    bindices, boffsets, q_acc2,
                                                    cache_k, cache_v, q_bf);
  k3_attn<<<dim3(16, 32), 256, 0, stream>>>(q_bf, cache_k, cache_v, blist,
                                            bgroups, bbias, num_acc, den_acc);
  k4_reduce_wuv<<<dim3(8, 32), 256, 0, stream>>>(num_acc, den_acc, W_UV, o_acc);
  k5_wo<<<dim3(16, 40), 256, 0, stream>>>(o_acc, W_O, out_part);
  k6_outsum<<<dim3(32, 5), 256, 0, stream>>>(out_part, out);
}